// Round 4
// baseline (1082.704 us; speedup 1.0000x reference)
//
#include <hip/hip_runtime.h>
#include <math.h>

// ---------------------------------------------------------------------------
// GCN_BAShapes: 3x (dense 128x128 -> gather-aggregate -> relu -> L2norm),
// concat -> linear(384x8) -> log_softmax.
// Strategy: build CSR-by-dst once (counts/scan/fill), then per layer:
//   dense_k (reg-blocked f32, W in LDS), agg_k (wave-per-node gather, fused
//   bias+relu+L2norm). Final fused linear+log_softmax.
// Edge dtype (int32 vs int64) auto-detected on device (odd-word probe).
// ---------------------------------------------------------------------------

__device__ __forceinline__ int edge_val(const int* e32, int is64, long long idx) {
  return is64 ? e32[idx * 2] : e32[idx];
}

__global__ void init_k(int* counts, int* cursor, int n) {
  int i = blockIdx.x * blockDim.x + threadIdx.x;
  int stride = gridDim.x * blockDim.x;
  for (; i < n; i += stride) { counts[i] = 0; cursor[i] = 0; }
}

// If the edge buffer is int64 (little-endian, values in [0,2^31)), every odd
// int32 word is 0. For int32 data the odd words are edge indices (random in
// [0,100000)) -> OR over 4096 of them is nonzero with overwhelming probability.
__global__ void detect_k(const int* e32, int* flag) {
  __shared__ int any;
  if (threadIdx.x == 0) any = 0;
  __syncthreads();
  int v = 0;
  for (int i = threadIdx.x; i < 4096; i += blockDim.x) v |= e32[2 * i + 1];
  if (v) atomicOr(&any, 1);
  __syncthreads();
  if (threadIdx.x == 0) *flag = (any == 0) ? 1 : 0;
}

__global__ void count_k(const int* e32, const int* flag, int* counts, int E) {
  int is64 = *flag;
  long long i = (long long)blockIdx.x * blockDim.x + threadIdx.x;
  long long stride = (long long)gridDim.x * blockDim.x;
  for (; i < E; i += stride) {
    int d = edge_val(e32, is64, (long long)E + i);
    atomicAdd(&counts[d], 1);
  }
}

__global__ __launch_bounds__(1024) void scan1_k(const int* counts, int* partials, int n) {
  __shared__ int sb[1024];
  int i = blockIdx.x * 1024 + threadIdx.x;
  sb[threadIdx.x] = (i < n) ? counts[i] : 0;
  __syncthreads();
  for (int off = 512; off > 0; off >>= 1) {
    if (threadIdx.x < off) sb[threadIdx.x] += sb[threadIdx.x + off];
    __syncthreads();
  }
  if (threadIdx.x == 0) partials[blockIdx.x] = sb[0];
}

__global__ void scan2_k(int* partials, int nb) {
  if (blockIdx.x == 0 && threadIdx.x == 0) {
    int run = 0;
    for (int i = 0; i < nb; i++) { int v = partials[i]; partials[i] = run; run += v; }
  }
}

__global__ __launch_bounds__(1024) void scan3_k(const int* counts, const int* partials,
                                                int* row_ptr, int n) {
  __shared__ int sb[1024];
  int i = blockIdx.x * 1024 + threadIdx.x;
  int v = (i < n) ? counts[i] : 0;
  sb[threadIdx.x] = v;
  __syncthreads();
  for (int off = 1; off < 1024; off <<= 1) {
    int add = (threadIdx.x >= (unsigned)off) ? sb[threadIdx.x - off] : 0;
    __syncthreads();
    sb[threadIdx.x] += add;
    __syncthreads();
  }
  if (i < n) row_ptr[i] = partials[blockIdx.x] + sb[threadIdx.x] - v;  // exclusive
}

__global__ void dinv_k(const int* counts, float* dinv, int n) {
  int i = blockIdx.x * blockDim.x + threadIdx.x;
  int stride = gridDim.x * blockDim.x;
  for (; i < n; i += stride) {
    // deg = in-edges + self-loop; always >= 1 so no zero guard needed
    dinv[i] = 1.0f / sqrtf((float)counts[i] + 1.0f);
  }
}

__global__ void fill_k(const int* e32, const int* flag, const int* row_ptr, int* cursor,
                       const float* dinv, int2* edata, int E) {
  int is64 = *flag;
  long long i = (long long)blockIdx.x * blockDim.x + threadIdx.x;
  long long stride = (long long)gridDim.x * blockDim.x;
  for (; i < E; i += stride) {
    int s = edge_val(e32, is64, i);
    int d = edge_val(e32, is64, (long long)E + i);
    int pos = atomicAdd(&cursor[d], 1);
    int idx = row_ptr[d] + pos;
    edata[idx] = make_int2(s, __float_as_int(dinv[s] * dinv[d]));
  }
}

// H = X @ W  (N x 128) @ (128 x 128). W staged in LDS (64 KB). Each block does
// a 64x128 tile; each thread 8 rows x 4 cols = 32 accumulators -> VALU-bound.
__global__ __launch_bounds__(256) void dense_k(const float* __restrict__ X,
                                               const float* __restrict__ W,
                                               float* __restrict__ Hout, int n) {
  __shared__ float Wl[128 * 128];
  for (int i = threadIdx.x; i < 4096; i += 256)
    ((float4*)Wl)[i] = ((const float4*)W)[i];
  __syncthreads();
  int cg = threadIdx.x & 31;   // col group: cols cg*4 .. cg*4+3
  int rg = threadIdx.x >> 5;   // 8 row groups
  int row0 = blockIdx.x * 64 + rg * 8;
  float4 acc[8];
#pragma unroll
  for (int r = 0; r < 8; r++) acc[r] = make_float4(0.f, 0.f, 0.f, 0.f);
  const float4* Wl4 = (const float4*)Wl;
  for (int k4 = 0; k4 < 32; k4++) {
    float4 w0 = Wl4[(k4 * 4 + 0) * 32 + cg];
    float4 w1 = Wl4[(k4 * 4 + 1) * 32 + cg];
    float4 w2 = Wl4[(k4 * 4 + 2) * 32 + cg];
    float4 w3 = Wl4[(k4 * 4 + 3) * 32 + cg];
#pragma unroll
    for (int r = 0; r < 8; r++) {
      int row = row0 + r; if (row >= n) row = n - 1;  // clamp loads, guard stores
      float4 xv = *(const float4*)(X + (size_t)row * 128 + k4 * 4);
      acc[r].x += xv.x * w0.x + xv.y * w1.x + xv.z * w2.x + xv.w * w3.x;
      acc[r].y += xv.x * w0.y + xv.y * w1.y + xv.z * w2.y + xv.w * w3.y;
      acc[r].z += xv.x * w0.z + xv.y * w1.z + xv.z * w2.z + xv.w * w3.z;
      acc[r].w += xv.x * w0.w + xv.y * w1.w + xv.z * w2.w + xv.w * w3.w;
    }
  }
#pragma unroll
  for (int r = 0; r < 8; r++) {
    int row = row0 + r;
    if (row < n) *(float4*)&Hout[(size_t)row * 128 + cg * 4] = acc[r];
  }
}

// One wave per node: gather h[src]*w over CSR in-edges + self-loop, then
// fused bias + relu + L2-normalize. float2 per lane covers 128 features.
__global__ __launch_bounds__(256) void agg_k(const float* __restrict__ H,
                                             const int2* __restrict__ edata,
                                             const int* __restrict__ row_ptr,
                                             const int* __restrict__ counts,
                                             const float* __restrict__ dinv,
                                             const float* __restrict__ bias,
                                             float* __restrict__ Out, int n) {
  int node = blockIdx.x * 4 + (threadIdx.x >> 6);
  if (node >= n) return;
  int lane = threadIdx.x & 63;
  float di = dinv[node];
  float2 h0 = *(const float2*)&H[(size_t)node * 128 + lane * 2];
  float ax = h0.x * di * di, ay = h0.y * di * di;  // self loop
  int start = row_ptr[node];
  int cnt = counts[node];
  for (int i = 0; i < cnt; i++) {
    int2 ed = edata[start + i];                 // wave-uniform broadcast load
    float w = __int_as_float(ed.y);
    float2 hv = *(const float2*)&H[(size_t)ed.x * 128 + lane * 2];
    ax += hv.x * w; ay += hv.y * w;
  }
  float2 bv = *(const float2*)&bias[lane * 2];
  ax = fmaxf(ax + bv.x, 0.f);
  ay = fmaxf(ay + bv.y, 0.f);
  float ss = ax * ax + ay * ay;
#pragma unroll
  for (int off = 32; off > 0; off >>= 1) ss += __shfl_xor(ss, off);
  float scale = 1.0f / fmaxf(sqrtf(ss), 1e-12f);
  float2 o = make_float2(ax * scale, ay * scale);
  *(float2*)&Out[(size_t)node * 128 + lane * 2] = o;
}

// logits = [O1|O2|O3] @ Wlin + blin, then log_softmax. Thread per node.
__global__ __launch_bounds__(256) void final_k(const float* __restrict__ O1,
                                               const float* __restrict__ O2,
                                               const float* __restrict__ O3,
                                               const float* __restrict__ Wlin,
                                               const float* __restrict__ blin,
                                               float* __restrict__ out, int n) {
  __shared__ float Wl[384 * 8];
  __shared__ float bl[8];
  for (int i = threadIdx.x; i < 384 * 8 / 4; i += 256)
    ((float4*)Wl)[i] = ((const float4*)Wlin)[i];
  if (threadIdx.x < 8) bl[threadIdx.x] = blin[threadIdx.x];
  __syncthreads();
  int node = blockIdx.x * 256 + threadIdx.x;
  if (node >= n) return;
  float acc[8];
#pragma unroll
  for (int c = 0; c < 8; c++) acc[c] = bl[c];
  const float* parts[3] = {O1, O2, O3};
  for (int p = 0; p < 3; p++) {
    const float4* e4 = (const float4*)(parts[p] + (size_t)node * 128);
    for (int k4 = 0; k4 < 32; k4++) {
      float4 v = e4[k4];
      const float4* wr = (const float4*)&Wl[(p * 128 + k4 * 4) * 8];
      float vv[4] = {v.x, v.y, v.z, v.w};
#pragma unroll
      for (int j = 0; j < 4; j++) {
        float4 wa = wr[j * 2], wb = wr[j * 2 + 1];
        acc[0] += vv[j] * wa.x; acc[1] += vv[j] * wa.y;
        acc[2] += vv[j] * wa.z; acc[3] += vv[j] * wa.w;
        acc[4] += vv[j] * wb.x; acc[5] += vv[j] * wb.y;
        acc[6] += vv[j] * wb.z; acc[7] += vv[j] * wb.w;
      }
    }
  }
  float mx = acc[0];
#pragma unroll
  for (int c = 1; c < 8; c++) mx = fmaxf(mx, acc[c]);
  float se = 0.f;
#pragma unroll
  for (int c = 0; c < 8; c++) se += expf(acc[c] - mx);
  float lse = mx + logf(se);
  float* o = out + (size_t)node * 8;
#pragma unroll
  for (int c = 0; c < 8; c++) o[c] = acc[c] - lse;
}

extern "C" void kernel_launch(void* const* d_in, const int* in_sizes, int n_in,
                              void* d_out, int out_size, void* d_ws, size_t ws_size,
                              hipStream_t stream) {
  const float* x    = (const float*)d_in[0];
  const int*   e32  = (const int*)d_in[1];
  const float* W1   = (const float*)d_in[2];
  const float* b1   = (const float*)d_in[3];
  const float* W2   = (const float*)d_in[4];
  const float* b2   = (const float*)d_in[5];
  const float* W3   = (const float*)d_in[6];
  const float* b3   = (const float*)d_in[7];
  const float* Wlin = (const float*)d_in[8];
  const float* blin = (const float*)d_in[9];
  float* out = (float*)d_out;

  const int Nn = in_sizes[0] / 128;
  const int E  = in_sizes[1] / 2;

  char* ws = (char*)d_ws;
  size_t off = 0;
  auto take = [&](size_t bytes) -> char* {
    char* p = ws + off;
    off = (off + bytes + 255) & ~(size_t)255;
    return p;
  };
  int*   flag   = (int*)  take(256);
  int*   counts = (int*)  take((size_t)Nn * 4);
  int*   cursor = (int*)  take((size_t)Nn * 4);
  int*   rowp   = (int*)  take((size_t)Nn * 4);
  float* dinv   = (float*)take((size_t)Nn * 4);
  int*   parts  = (int*)  take(4096);
  int2*  edata  = (int2*) take((size_t)E * 8);
  float* Hb     = (float*)take((size_t)Nn * 128 * 4);
  float* O1     = (float*)take((size_t)Nn * 128 * 4);
  float* O2     = (float*)take((size_t)Nn * 128 * 4);
  float* O3     = (float*)take((size_t)Nn * 128 * 4);

  int nb = (Nn + 1023) / 1024;
  int dense_grid = (Nn + 63) / 64;
  int agg_grid = (Nn + 3) / 4;

  hipLaunchKernelGGL(init_k,   dim3(256),  dim3(256),  0, stream, counts, cursor, Nn);
  hipLaunchKernelGGL(detect_k, dim3(1),    dim3(256),  0, stream, e32, flag);
  hipLaunchKernelGGL(count_k,  dim3(2048), dim3(256),  0, stream, e32, flag, counts, E);
  hipLaunchKernelGGL(scan1_k,  dim3(nb),   dim3(1024), 0, stream, counts, parts, Nn);
  hipLaunchKernelGGL(scan2_k,  dim3(1),    dim3(1),    0, stream, parts, nb);
  hipLaunchKernelGGL(scan3_k,  dim3(nb),   dim3(1024), 0, stream, counts, parts, rowp, Nn);
  hipLaunchKernelGGL(dinv_k,   dim3(256),  dim3(256),  0, stream, counts, dinv, Nn);
  hipLaunchKernelGGL(fill_k,   dim3(2048), dim3(256),  0, stream, e32, flag, rowp, cursor, dinv, edata, E);

  hipLaunchKernelGGL(dense_k, dim3(dense_grid), dim3(256), 0, stream, x,  W1, Hb, Nn);
  hipLaunchKernelGGL(agg_k,   dim3(agg_grid),   dim3(256), 0, stream, Hb, edata, rowp, counts, dinv, b1, O1, Nn);
  hipLaunchKernelGGL(dense_k, dim3(dense_grid), dim3(256), 0, stream, O1, W2, Hb, Nn);
  hipLaunchKernelGGL(agg_k,   dim3(agg_grid),   dim3(256), 0, stream, Hb, edata, rowp, counts, dinv, b2, O2, Nn);
  hipLaunchKernelGGL(dense_k, dim3(dense_grid), dim3(256), 0, stream, O2, W3, Hb, Nn);
  hipLaunchKernelGGL(agg_k,   dim3(agg_grid),   dim3(256), 0, stream, Hb, edata, rowp, counts, dinv, b3, O3, Nn);
  hipLaunchKernelGGL(final_k, dim3((Nn + 255) / 256), dim3(256), 0, stream, O1, O2, O3, Wlin, blin, out, Nn);
}

// Round 5
// 743.809 us; speedup vs baseline: 1.4556x; 1.4556x over previous
//
#include <hip/hip_runtime.h>
#include <math.h>

// ---------------------------------------------------------------------------
// GCN_BAShapes: 3x (dense 128x128 -> gather-aggregate -> relu -> L2norm),
// concat -> linear(384x8) -> log_softmax.
// R5: H stored as bf16 (gather traffic halved: 417MB->~220MB FETCH/dispatch),
//     agg edge-data via coalesced load + shfl broadcast, 4-wide unrolled
//     gathers for MLP. O1..O3 remain f32 (single bf16 rounding per layer).
// ---------------------------------------------------------------------------

__device__ __forceinline__ int edge_val(const int* e32, int is64, long long idx) {
  return is64 ? e32[idx * 2] : e32[idx];
}

__device__ __forceinline__ unsigned short f2bf(float f) {
  unsigned int u = __float_as_uint(f);
  u += 0x7fff + ((u >> 16) & 1);  // round-to-nearest-even
  return (unsigned short)(u >> 16);
}

__device__ __forceinline__ float2 bfpair(unsigned int u) {
  // low 16 bits = feat 2l, high 16 bits = feat 2l+1
  return make_float2(__uint_as_float(u << 16), __uint_as_float(u & 0xffff0000u));
}

// init counts/cursor; block 0 also detects edge dtype (int64 -> odd words 0)
__global__ void prep_k(const int* e32, int* flag, int* counts, int* cursor, int n) {
  int stride = gridDim.x * blockDim.x;
  for (int j = blockIdx.x * blockDim.x + threadIdx.x; j < n; j += stride) {
    counts[j] = 0; cursor[j] = 0;
  }
  if (blockIdx.x == 0) {
    __shared__ int any;
    if (threadIdx.x == 0) any = 0;
    __syncthreads();
    int v = 0;
    for (int k = threadIdx.x; k < 4096; k += blockDim.x) v |= e32[2 * k + 1];
    if (v) atomicOr(&any, 1);
    __syncthreads();
    if (threadIdx.x == 0) *flag = (any == 0) ? 1 : 0;
  }
}

__global__ void count_k(const int* e32, const int* flag, int* counts, int E) {
  int is64 = *flag;
  long long i = (long long)blockIdx.x * blockDim.x + threadIdx.x;
  long long stride = (long long)gridDim.x * blockDim.x;
  for (; i < E; i += stride) {
    int d = edge_val(e32, is64, (long long)E + i);
    atomicAdd(&counts[d], 1);
  }
}

// block-sum of counts into partials; also dinv = 1/sqrt(deg+1)
__global__ __launch_bounds__(1024) void scan1_k(const int* counts, int* partials,
                                                float* dinv, int n) {
  __shared__ int sb[1024];
  int i = blockIdx.x * 1024 + threadIdx.x;
  int v = (i < n) ? counts[i] : 0;
  if (i < n) dinv[i] = 1.0f / sqrtf((float)v + 1.0f);
  sb[threadIdx.x] = v;
  __syncthreads();
  for (int off = 512; off > 0; off >>= 1) {
    if (threadIdx.x < off) sb[threadIdx.x] += sb[threadIdx.x + off];
    __syncthreads();
  }
  if (threadIdx.x == 0) partials[blockIdx.x] = sb[0];
}

__global__ void scan2_k(int* partials, int nb) {
  if (blockIdx.x == 0 && threadIdx.x == 0) {
    int run = 0;
    for (int i = 0; i < nb; i++) { int v = partials[i]; partials[i] = run; run += v; }
  }
}

__global__ __launch_bounds__(1024) void scan3_k(const int* counts, const int* partials,
                                                int* row_ptr, int n) {
  __shared__ int sb[1024];
  int i = blockIdx.x * 1024 + threadIdx.x;
  int v = (i < n) ? counts[i] : 0;
  sb[threadIdx.x] = v;
  __syncthreads();
  for (int off = 1; off < 1024; off <<= 1) {
    int add = (threadIdx.x >= (unsigned)off) ? sb[threadIdx.x - off] : 0;
    __syncthreads();
    sb[threadIdx.x] += add;
    __syncthreads();
  }
  if (i < n) row_ptr[i] = partials[blockIdx.x] + sb[threadIdx.x] - v;  // exclusive
}

__global__ void fill_k(const int* e32, const int* flag, const int* row_ptr, int* cursor,
                       const float* dinv, int2* edata, int E) {
  int is64 = *flag;
  long long i = (long long)blockIdx.x * blockDim.x + threadIdx.x;
  long long stride = (long long)gridDim.x * blockDim.x;
  for (; i < E; i += stride) {
    int s = edge_val(e32, is64, i);
    int d = edge_val(e32, is64, (long long)E + i);
    int pos = atomicAdd(&cursor[d], 1);
    int idx = row_ptr[d] + pos;
    edata[idx] = make_int2(s, __float_as_int(dinv[s] * dinv[d]));
  }
}

// H = X @ W, output rounded to bf16. W staged in LDS. 64-row tile per block,
// each thread 8 rows x 4 cols.
__global__ __launch_bounds__(256) void dense_k(const float* __restrict__ X,
                                               const float* __restrict__ W,
                                               unsigned short* __restrict__ Hout, int n) {
  __shared__ float Wl[128 * 128];
  for (int i = threadIdx.x; i < 4096; i += 256)
    ((float4*)Wl)[i] = ((const float4*)W)[i];
  __syncthreads();
  int cg = threadIdx.x & 31;   // col group: cols cg*4 .. cg*4+3
  int rg = threadIdx.x >> 5;   // 8 row groups
  int row0 = blockIdx.x * 64 + rg * 8;
  float4 acc[8];
#pragma unroll
  for (int r = 0; r < 8; r++) acc[r] = make_float4(0.f, 0.f, 0.f, 0.f);
  const float4* Wl4 = (const float4*)Wl;
  for (int k4 = 0; k4 < 32; k4++) {
    float4 w0 = Wl4[(k4 * 4 + 0) * 32 + cg];
    float4 w1 = Wl4[(k4 * 4 + 1) * 32 + cg];
    float4 w2 = Wl4[(k4 * 4 + 2) * 32 + cg];
    float4 w3 = Wl4[(k4 * 4 + 3) * 32 + cg];
#pragma unroll
    for (int r = 0; r < 8; r++) {
      int row = row0 + r; if (row >= n) row = n - 1;  // clamp loads, guard stores
      float4 xv = *(const float4*)(X + (size_t)row * 128 + k4 * 4);
      acc[r].x += xv.x * w0.x + xv.y * w1.x + xv.z * w2.x + xv.w * w3.x;
      acc[r].y += xv.x * w0.y + xv.y * w1.y + xv.z * w2.y + xv.w * w3.y;
      acc[r].z += xv.x * w0.z + xv.y * w1.z + xv.z * w2.z + xv.w * w3.z;
      acc[r].w += xv.x * w0.w + xv.y * w1.w + xv.z * w2.w + xv.w * w3.w;
    }
  }
#pragma unroll
  for (int r = 0; r < 8; r++) {
    int row = row0 + r;
    if (row < n) {
      unsigned int u0 = (unsigned int)f2bf(acc[r].x) | ((unsigned int)f2bf(acc[r].y) << 16);
      unsigned int u1 = (unsigned int)f2bf(acc[r].z) | ((unsigned int)f2bf(acc[r].w) << 16);
      *(uint2*)&Hout[(size_t)row * 128 + cg * 4] = make_uint2(u0, u1);
    }
  }
}

// One wave per node: gather bf16 h[src]*w over CSR in-edges + self-loop, fused
// bias + relu + L2norm, f32 output. Edge (src,w) batch-loaded coalesced then
// shfl-broadcast; gathers unrolled 4-wide for memory-level parallelism.
__global__ __launch_bounds__(256) void agg_k(const unsigned short* __restrict__ H,
                                             const int2* __restrict__ edata,
                                             const int* __restrict__ row_ptr,
                                             const int* __restrict__ counts,
                                             const float* __restrict__ dinv,
                                             const float* __restrict__ bias,
                                             float* __restrict__ Out, int n) {
  int node = blockIdx.x * 4 + (threadIdx.x >> 6);
  if (node >= n) return;
  int lane = threadIdx.x & 63;
  float di = dinv[node];
  float wself = di * di;
  unsigned int us = *(const unsigned int*)(H + (size_t)node * 128 + lane * 2);
  float2 hs = bfpair(us);
  float ax = hs.x * wself, ay = hs.y * wself;
  int start = row_ptr[node];
  int cnt = counts[node];
  for (int base = 0; base < cnt; base += 64) {
    int m = min(64, cnt - base);
    int2 me = (lane < m) ? edata[start + base + lane] : make_int2(0, 0);
    int i = 0;
    for (; i + 4 <= m; i += 4) {
      int s0 = __shfl(me.x, i),     s1 = __shfl(me.x, i + 1);
      int s2 = __shfl(me.x, i + 2), s3 = __shfl(me.x, i + 3);
      float w0 = __int_as_float(__shfl(me.y, i));
      float w1 = __int_as_float(__shfl(me.y, i + 1));
      float w2 = __int_as_float(__shfl(me.y, i + 2));
      float w3 = __int_as_float(__shfl(me.y, i + 3));
      unsigned int u0 = *(const unsigned int*)(H + (size_t)s0 * 128 + lane * 2);
      unsigned int u1 = *(const unsigned int*)(H + (size_t)s1 * 128 + lane * 2);
      unsigned int u2 = *(const unsigned int*)(H + (size_t)s2 * 128 + lane * 2);
      unsigned int u3 = *(const unsigned int*)(H + (size_t)s3 * 128 + lane * 2);
      float2 f0 = bfpair(u0), f1 = bfpair(u1), f2 = bfpair(u2), f3 = bfpair(u3);
      ax += f0.x * w0 + f1.x * w1 + f2.x * w2 + f3.x * w3;
      ay += f0.y * w0 + f1.y * w1 + f2.y * w2 + f3.y * w3;
    }
    for (; i < m; i++) {
      int s0 = __shfl(me.x, i);
      float w0 = __int_as_float(__shfl(me.y, i));
      unsigned int u0 = *(const unsigned int*)(H + (size_t)s0 * 128 + lane * 2);
      float2 f0 = bfpair(u0);
      ax += f0.x * w0;
      ay += f0.y * w0;
    }
  }
  float2 bv = *(const float2*)&bias[lane * 2];
  ax = fmaxf(ax + bv.x, 0.f);
  ay = fmaxf(ay + bv.y, 0.f);
  float ss = ax * ax + ay * ay;
#pragma unroll
  for (int off = 32; off > 0; off >>= 1) ss += __shfl_xor(ss, off);
  float scale = 1.0f / fmaxf(sqrtf(ss), 1e-12f);
  *(float2*)&Out[(size_t)node * 128 + lane * 2] = make_float2(ax * scale, ay * scale);
}

// logits = [O1|O2|O3] @ Wlin + blin, then log_softmax. Thread per node.
__global__ __launch_bounds__(256) void final_k(const float* __restrict__ O1,
                                               const float* __restrict__ O2,
                                               const float* __restrict__ O3,
                                               const float* __restrict__ Wlin,
                                               const float* __restrict__ blin,
                                               float* __restrict__ out, int n) {
  __shared__ float Wl[384 * 8];
  __shared__ float bl[8];
  for (int i = threadIdx.x; i < 384 * 8 / 4; i += 256)
    ((float4*)Wl)[i] = ((const float4*)Wlin)[i];
  if (threadIdx.x < 8) bl[threadIdx.x] = blin[threadIdx.x];
  __syncthreads();
  int node = blockIdx.x * 256 + threadIdx.x;
  if (node >= n) return;
  float acc[8];
#pragma unroll
  for (int c = 0; c < 8; c++) acc[c] = bl[c];
  const float* parts[3] = {O1, O2, O3};
  for (int p = 0; p < 3; p++) {
    const float4* e4 = (const float4*)(parts[p] + (size_t)node * 128);
    for (int k4 = 0; k4 < 32; k4++) {
      float4 v = e4[k4];
      const float4* wr = (const float4*)&Wl[(p * 128 + k4 * 4) * 8];
      float vv[4] = {v.x, v.y, v.z, v.w};
#pragma unroll
      for (int j = 0; j < 4; j++) {
        float4 wa = wr[j * 2], wb = wr[j * 2 + 1];
        acc[0] += vv[j] * wa.x; acc[1] += vv[j] * wa.y;
        acc[2] += vv[j] * wa.z; acc[3] += vv[j] * wa.w;
        acc[4] += vv[j] * wb.x; acc[5] += vv[j] * wb.y;
        acc[6] += vv[j] * wb.z; acc[7] += vv[j] * wb.w;
      }
    }
  }
  float mx = acc[0];
#pragma unroll
  for (int c = 1; c < 8; c++) mx = fmaxf(mx, acc[c]);
  float se = 0.f;
#pragma unroll
  for (int c = 0; c < 8; c++) se += expf(acc[c] - mx);
  float lse = mx + logf(se);
  float* o = out + (size_t)node * 8;
#pragma unroll
  for (int c = 0; c < 8; c++) o[c] = acc[c] - lse;
}

extern "C" void kernel_launch(void* const* d_in, const int* in_sizes, int n_in,
                              void* d_out, int out_size, void* d_ws, size_t ws_size,
                              hipStream_t stream) {
  const float* x    = (const float*)d_in[0];
  const int*   e32  = (const int*)d_in[1];
  const float* W1   = (const float*)d_in[2];
  const float* b1   = (const float*)d_in[3];
  const float* W2   = (const float*)d_in[4];
  const float* b2   = (const float*)d_in[5];
  const float* W3   = (const float*)d_in[6];
  const float* b3   = (const float*)d_in[7];
  const float* Wlin = (const float*)d_in[8];
  const float* blin = (const float*)d_in[9];
  float* out = (float*)d_out;

  const int Nn = in_sizes[0] / 128;
  const int E  = in_sizes[1] / 2;

  char* ws = (char*)d_ws;
  size_t off = 0;
  auto take = [&](size_t bytes) -> char* {
    char* p = ws + off;
    off = (off + bytes + 255) & ~(size_t)255;
    return p;
  };
  int*   flag   = (int*)  take(256);
  int*   counts = (int*)  take((size_t)Nn * 4);
  int*   cursor = (int*)  take((size_t)Nn * 4);
  int*   rowp   = (int*)  take((size_t)Nn * 4);
  float* dinv   = (float*)take((size_t)Nn * 4);
  int*   parts  = (int*)  take(4096);
  int2*  edata  = (int2*) take((size_t)E * 8);
  unsigned short* Hb = (unsigned short*)take((size_t)Nn * 128 * 2);
  float* O1     = (float*)take((size_t)Nn * 128 * 4);
  float* O2     = (float*)take((size_t)Nn * 128 * 4);
  float* O3     = (float*)take((size_t)Nn * 128 * 4);

  int nb = (Nn + 1023) / 1024;
  int dense_grid = (Nn + 63) / 64;
  int agg_grid = (Nn + 3) / 4;

  hipLaunchKernelGGL(prep_k,  dim3(256),  dim3(256),  0, stream, e32, flag, counts, cursor, Nn);
  hipLaunchKernelGGL(count_k, dim3(2048), dim3(256),  0, stream, e32, flag, counts, E);
  hipLaunchKernelGGL(scan1_k, dim3(nb),   dim3(1024), 0, stream, counts, parts, dinv, Nn);
  hipLaunchKernelGGL(scan2_k, dim3(1),    dim3(1),    0, stream, parts, nb);
  hipLaunchKernelGGL(scan3_k, dim3(nb),   dim3(1024), 0, stream, counts, parts, rowp, Nn);
  hipLaunchKernelGGL(fill_k,  dim3(2048), dim3(256),  0, stream, e32, flag, rowp, cursor, dinv, edata, E);

  hipLaunchKernelGGL(dense_k, dim3(dense_grid), dim3(256), 0, stream, x,  W1, Hb, Nn);
  hipLaunchKernelGGL(agg_k,   dim3(agg_grid),   dim3(256), 0, stream, Hb, edata, rowp, counts, dinv, b1, O1, Nn);
  hipLaunchKernelGGL(dense_k, dim3(dense_grid), dim3(256), 0, stream, O1, W2, Hb, Nn);
  hipLaunchKernelGGL(agg_k,   dim3(agg_grid),   dim3(256), 0, stream, Hb, edata, rowp, counts, dinv, b2, O2, Nn);
  hipLaunchKernelGGL(dense_k, dim3(dense_grid), dim3(256), 0, stream, O2, W3, Hb, Nn);
  hipLaunchKernelGGL(agg_k,   dim3(agg_grid),   dim3(256), 0, stream, Hb, edata, rowp, counts, dinv, b3, O3, Nn);
  hipLaunchKernelGGL(final_k, dim3((Nn + 255) / 256), dim3(256), 0, stream, O1, O2, O3, Wlin, blin, out, Nn);
}

// Round 8
// 605.836 us; speedup vs baseline: 1.7871x; 1.2277x over previous
//
#include <hip/hip_runtime.h>
#include <math.h>

// ---------------------------------------------------------------------------
// GCN_BAShapes: 3x (dense 128x128 -> gather-aggregate -> relu -> L2norm),
// concat -> linear(384x8) -> log_softmax.
// R6: dense via bf16 MFMA 16x16x32 (no LDS, Wt pre-transposed bf16 in L1),
//     all activations bf16 (agg writes bf16, final reads bf16).
// ---------------------------------------------------------------------------

typedef __attribute__((ext_vector_type(8))) short short8;
typedef __attribute__((ext_vector_type(4))) float float4v;

__device__ __forceinline__ int edge_val(const int* e32, int is64, long long idx) {
  return is64 ? e32[idx * 2] : e32[idx];
}

__device__ __forceinline__ unsigned short f2bf(float f) {
  unsigned int u = __float_as_uint(f);
  u += 0x7fff + ((u >> 16) & 1);  // round-to-nearest-even
  return (unsigned short)(u >> 16);
}

__device__ __forceinline__ float bf2f(unsigned short h) {
  return __uint_as_float((unsigned int)h << 16);
}

__device__ __forceinline__ float2 bfpair(unsigned int u) {
  return make_float2(__uint_as_float(u << 16), __uint_as_float(u & 0xffff0000u));
}

// init counts/cursor; block 0 also detects edge dtype (int64 -> odd words 0)
__global__ void prep_k(const int* e32, int* flag, int* counts, int* cursor, int n) {
  int stride = gridDim.x * blockDim.x;
  for (int j = blockIdx.x * blockDim.x + threadIdx.x; j < n; j += stride) {
    counts[j] = 0; cursor[j] = 0;
  }
  if (blockIdx.x == 0) {
    __shared__ int any;
    if (threadIdx.x == 0) any = 0;
    __syncthreads();
    int v = 0;
    for (int k = threadIdx.x; k < 4096; k += blockDim.x) v |= e32[2 * k + 1];
    if (v) atomicOr(&any, 1);
    __syncthreads();
    if (threadIdx.x == 0) *flag = (any == 0) ? 1 : 0;
  }
}

__global__ void count_k(const int* e32, const int* flag, int* counts, int E) {
  int is64 = *flag;
  long long i = (long long)blockIdx.x * blockDim.x + threadIdx.x;
  long long stride = (long long)gridDim.x * blockDim.x;
  for (; i < E; i += stride) {
    int d = edge_val(e32, is64, (long long)E + i);
    atomicAdd(&counts[d], 1);
  }
}

// block-sum of counts into partials; also dinv = 1/sqrt(deg+1)
__global__ __launch_bounds__(1024) void scan1_k(const int* counts, int* partials,
                                                float* dinv, int n) {
  __shared__ int sb[1024];
  int i = blockIdx.x * 1024 + threadIdx.x;
  int v = (i < n) ? counts[i] : 0;
  if (i < n) dinv[i] = 1.0f / sqrtf((float)v + 1.0f);
  sb[threadIdx.x] = v;
  __syncthreads();
  for (int off = 512; off > 0; off >>= 1) {
    if (threadIdx.x < off) sb[threadIdx.x] += sb[threadIdx.x + off];
    __syncthreads();
  }
  if (threadIdx.x == 0) partials[blockIdx.x] = sb[0];
}

__global__ void scan2_k(int* partials, int nb) {
  if (blockIdx.x == 0 && threadIdx.x == 0) {
    int run = 0;
    for (int i = 0; i < nb; i++) { int v = partials[i]; partials[i] = run; run += v; }
  }
}

__global__ __launch_bounds__(1024) void scan3_k(const int* counts, const int* partials,
                                                int* row_ptr, int n) {
  __shared__ int sb[1024];
  int i = blockIdx.x * 1024 + threadIdx.x;
  int v = (i < n) ? counts[i] : 0;
  sb[threadIdx.x] = v;
  __syncthreads();
  for (int off = 1; off < 1024; off <<= 1) {
    int add = (threadIdx.x >= (unsigned)off) ? sb[threadIdx.x - off] : 0;
    __syncthreads();
    sb[threadIdx.x] += add;
    __syncthreads();
  }
  if (i < n) row_ptr[i] = partials[blockIdx.x] + sb[threadIdx.x] - v;  // exclusive
}

__global__ void fill_k(const int* e32, const int* flag, const int* row_ptr, int* cursor,
                       const float* dinv, int2* edata, int E) {
  int is64 = *flag;
  long long i = (long long)blockIdx.x * blockDim.x + threadIdx.x;
  long long stride = (long long)gridDim.x * blockDim.x;
  for (; i < E; i += stride) {
    int s = edge_val(e32, is64, i);
    int d = edge_val(e32, is64, (long long)E + i);
    int pos = atomicAdd(&cursor[d], 1);
    int idx = row_ptr[d] + pos;
    edata[idx] = make_int2(s, __float_as_int(dinv[s] * dinv[d]));
  }
}

// Wt[col][k] bf16  <-  W[k][col] f32   (128x128, one launch per layer)
__global__ void wconv_k(const float* __restrict__ W, unsigned short* __restrict__ Wt) {
  int t = blockIdx.x * blockDim.x + threadIdx.x;  // t = col*128 + k
  if (t >= 128 * 128) return;
  int col = t >> 7, k = t & 127;
  Wt[t] = f2bf(W[k * 128 + col]);
}

// xb bf16 <- x f32 (vectorized: float4 -> 4 bf16)
__global__ void xconv_k(const float* __restrict__ x, unsigned short* __restrict__ xb,
                        int total4) {
  int i = blockIdx.x * blockDim.x + threadIdx.x;
  int stride = gridDim.x * blockDim.x;
  for (; i < total4; i += stride) {
    float4 v = ((const float4*)x)[i];
    unsigned int u0 = (unsigned int)f2bf(v.x) | ((unsigned int)f2bf(v.y) << 16);
    unsigned int u1 = (unsigned int)f2bf(v.z) | ((unsigned int)f2bf(v.w) << 16);
    ((uint2*)xb)[i] = make_uint2(u0, u1);
  }
}

// H = Xb @ W via mfma_f32_16x16x32_bf16. 4 waves/block, wave owns 16x128 strip.
// A[m][k]: lane=(k/8)*16+m holds k%8..; B[k][n]: lane=(k/8)*16+n; D: col=lane&15,
// row=(lane>>4)*4+reg (HW-verified C/D mapping). Wt is [col][k] bf16 (32 KB, L1).
__global__ __launch_bounds__(256) void dense_mfma_k(
    const unsigned short* __restrict__ Xb, const unsigned short* __restrict__ Wt,
    unsigned short* __restrict__ Hout, int n) {
  int wave = threadIdx.x >> 6;
  int lane = threadIdx.x & 63;
  int row0 = blockIdx.x * 64 + wave * 16;
  int lm = lane & 15;        // m (A) / n-within-tile (B) / col (D)
  int lk = lane >> 4;        // k-group 0..3
  int arow = row0 + lm; if (arow >= n) arow = n - 1;
  const unsigned short* xp = Xb + (size_t)arow * 128 + lk * 8;
  short8 a[4];
#pragma unroll
  for (int kk = 0; kk < 4; kk++)
    a[kk] = *reinterpret_cast<const short8*>(xp + kk * 32);
#pragma unroll
  for (int nt = 0; nt < 8; nt++) {
    float4v acc = {0.f, 0.f, 0.f, 0.f};
    const unsigned short* wp = Wt + (size_t)(nt * 16 + lm) * 128 + lk * 8;
#pragma unroll
    for (int kk = 0; kk < 4; kk++) {
      short8 b = *reinterpret_cast<const short8*>(wp + kk * 32);
      acc = __builtin_amdgcn_mfma_f32_16x16x32_bf16(a[kk], b, acc, 0, 0, 0);
    }
    int col = nt * 16 + lm;
#pragma unroll
    for (int r = 0; r < 4; r++) {
      int row = row0 + lk * 4 + r;
      if (row < n) Hout[(size_t)row * 128 + col] = f2bf(acc[r]);
    }
  }
}

// One wave per node: gather bf16 h[src]*w over CSR in-edges + self-loop, fused
// bias + relu + L2norm, bf16 output.
__global__ __launch_bounds__(256) void agg_k(const unsigned short* __restrict__ H,
                                             const int2* __restrict__ edata,
                                             const int* __restrict__ row_ptr,
                                             const int* __restrict__ counts,
                                             const float* __restrict__ dinv,
                                             const float* __restrict__ bias,
                                             unsigned short* __restrict__ Out, int n) {
  int node = blockIdx.x * 4 + (threadIdx.x >> 6);
  if (node >= n) return;
  int lane = threadIdx.x & 63;
  float di = dinv[node];
  float wself = di * di;
  unsigned int us = *(const unsigned int*)(H + (size_t)node * 128 + lane * 2);
  float2 hs = bfpair(us);
  float ax = hs.x * wself, ay = hs.y * wself;
  int start = row_ptr[node];
  int cnt = counts[node];
  for (int base = 0; base < cnt; base += 64) {
    int m = min(64, cnt - base);
    int2 me = (lane < m) ? edata[start + base + lane] : make_int2(0, 0);
    int i = 0;
    for (; i + 4 <= m; i += 4) {
      int s0 = __shfl(me.x, i),     s1 = __shfl(me.x, i + 1);
      int s2 = __shfl(me.x, i + 2), s3 = __shfl(me.x, i + 3);
      float w0 = __int_as_float(__shfl(me.y, i));
      float w1 = __int_as_float(__shfl(me.y, i + 1));
      float w2 = __int_as_float(__shfl(me.y, i + 2));
      float w3 = __int_as_float(__shfl(me.y, i + 3));
      unsigned int u0 = *(const unsigned int*)(H + (size_t)s0 * 128 + lane * 2);
      unsigned int u1 = *(const unsigned int*)(H + (size_t)s1 * 128 + lane * 2);
      unsigned int u2 = *(const unsigned int*)(H + (size_t)s2 * 128 + lane * 2);
      unsigned int u3 = *(const unsigned int*)(H + (size_t)s3 * 128 + lane * 2);
      float2 f0 = bfpair(u0), f1 = bfpair(u1), f2 = bfpair(u2), f3 = bfpair(u3);
      ax += f0.x * w0 + f1.x * w1 + f2.x * w2 + f3.x * w3;
      ay += f0.y * w0 + f1.y * w1 + f2.y * w2 + f3.y * w3;
    }
    for (; i < m; i++) {
      int s0 = __shfl(me.x, i);
      float w0 = __int_as_float(__shfl(me.y, i));
      float2 f0 = bfpair(*(const unsigned int*)(H + (size_t)s0 * 128 + lane * 2));
      ax += f0.x * w0;
      ay += f0.y * w0;
    }
  }
  float2 bv = *(const float2*)&bias[lane * 2];
  ax = fmaxf(ax + bv.x, 0.f);
  ay = fmaxf(ay + bv.y, 0.f);
  float ss = ax * ax + ay * ay;
#pragma unroll
  for (int off = 32; off > 0; off >>= 1) ss += __shfl_xor(ss, off);
  float scale = 1.0f / fmaxf(sqrtf(ss), 1e-12f);
  unsigned int po = (unsigned int)f2bf(ax * scale) | ((unsigned int)f2bf(ay * scale) << 16);
  *(unsigned int*)(Out + (size_t)node * 128 + lane * 2) = po;
}

// logits = [O1|O2|O3](bf16) @ Wlin + blin, then log_softmax. Thread per node.
__global__ __launch_bounds__(256) void final_k(const unsigned short* __restrict__ O1,
                                               const unsigned short* __restrict__ O2,
                                               const unsigned short* __restrict__ O3,
                                               const float* __restrict__ Wlin,
                                               const float* __restrict__ blin,
                                               float* __restrict__ out, int n) {
  __shared__ float Wl[384 * 8];
  __shared__ float bl[8];
  for (int i = threadIdx.x; i < 384 * 8 / 4; i += 256)
    ((float4*)Wl)[i] = ((const float4*)Wlin)[i];
  if (threadIdx.x < 8) bl[threadIdx.x] = blin[threadIdx.x];
  __syncthreads();
  int node = blockIdx.x * 256 + threadIdx.x;
  if (node >= n) return;
  float acc[8];
#pragma unroll
  for (int c = 0; c < 8; c++) acc[c] = bl[c];
  const unsigned short* parts[3] = {O1, O2, O3};
  for (int p = 0; p < 3; p++) {
    const uint2* e2 = (const uint2*)(parts[p] + (size_t)node * 128);
    for (int k4 = 0; k4 < 32; k4++) {
      uint2 v = e2[k4];
      float2 fa = bfpair(v.x), fb = bfpair(v.y);
      float vv[4] = {fa.x, fa.y, fb.x, fb.y};
      const float4* wr = (const float4*)&Wl[(p * 128 + k4 * 4) * 8];
#pragma unroll
      for (int j = 0; j < 4; j++) {
        float4 wa = wr[j * 2], wb = wr[j * 2 + 1];
        acc[0] += vv[j] * wa.x; acc[1] += vv[j] * wa.y;
        acc[2] += vv[j] * wa.z; acc[3] += vv[j] * wa.w;
        acc[4] += vv[j] * wb.x; acc[5] += vv[j] * wb.y;
        acc[6] += vv[j] * wb.z; acc[7] += vv[j] * wb.w;
      }
    }
  }
  float mx = acc[0];
#pragma unroll
  for (int c = 1; c < 8; c++) mx = fmaxf(mx, acc[c]);
  float se = 0.f;
#pragma unroll
  for (int c = 0; c < 8; c++) se += expf(acc[c] - mx);
  float lse = mx + logf(se);
  float* o = out + (size_t)node * 8;
#pragma unroll
  for (int c = 0; c < 8; c++) o[c] = acc[c] - lse;
}

extern "C" void kernel_launch(void* const* d_in, const int* in_sizes, int n_in,
                              void* d_out, int out_size, void* d_ws, size_t ws_size,
                              hipStream_t stream) {
  const float* x    = (const float*)d_in[0];
  const int*   e32  = (const int*)d_in[1];
  const float* W1   = (const float*)d_in[2];
  const float* b1   = (const float*)d_in[3];
  const float* W2   = (const float*)d_in[4];
  const float* b2   = (const float*)d_in[5];
  const float* W3   = (const float*)d_in[6];
  const float* b3   = (const float*)d_in[7];
  const float* Wlin = (const float*)d_in[8];
  const float* blin = (const float*)d_in[9];
  float* out = (float*)d_out;

  const int Nn = in_sizes[0] / 128;
  const int E  = in_sizes[1] / 2;

  char* ws = (char*)d_ws;
  size_t off = 0;
  auto take = [&](size_t bytes) -> char* {
    char* p = ws + off;
    off = (off + bytes + 255) & ~(size_t)255;
    return p;
  };
  int*   flag   = (int*)  take(256);
  int*   counts = (int*)  take((size_t)Nn * 4);
  int*   cursor = (int*)  take((size_t)Nn * 4);
  int*   rowp   = (int*)  take((size_t)Nn * 4);
  float* dinv   = (float*)take((size_t)Nn * 4);
  int*   parts  = (int*)  take(4096);
  int2*  edata  = (int2*) take((size_t)E * 8);
  unsigned short* xb  = (unsigned short*)take((size_t)Nn * 128 * 2);
  unsigned short* Hb  = (unsigned short*)take((size_t)Nn * 128 * 2);
  unsigned short* O1  = (unsigned short*)take((size_t)Nn * 128 * 2);
  unsigned short* O2  = (unsigned short*)take((size_t)Nn * 128 * 2);
  unsigned short* O3  = (unsigned short*)take((size_t)Nn * 128 * 2);
  unsigned short* Wt1 = (unsigned short*)take(128 * 128 * 2);
  unsigned short* Wt2 = (unsigned short*)take(128 * 128 * 2);
  unsigned short* Wt3 = (unsigned short*)take(128 * 128 * 2);

  int nb = (Nn + 1023) / 1024;
  int dense_grid = (Nn + 63) / 64;
  int agg_grid = (Nn + 3) / 4;

  hipLaunchKernelGGL(prep_k,  dim3(256),  dim3(256),  0, stream, e32, flag, counts, cursor, Nn);
  hipLaunchKernelGGL(count_k, dim3(2048), dim3(256),  0, stream, e32, flag, counts, E);
  hipLaunchKernelGGL(scan1_k, dim3(nb),   dim3(1024), 0, stream, counts, parts, dinv, Nn);
  hipLaunchKernelGGL(scan2_k, dim3(1),    dim3(1),    0, stream, parts, nb);
  hipLaunchKernelGGL(scan3_k, dim3(nb),   dim3(1024), 0, stream, counts, parts, rowp, Nn);
  hipLaunchKernelGGL(fill_k,  dim3(2048), dim3(256),  0, stream, e32, flag, rowp, cursor, dinv, edata, E);

  hipLaunchKernelGGL(wconv_k, dim3(64), dim3(256), 0, stream, W1, Wt1);
  hipLaunchKernelGGL(wconv_k, dim3(64), dim3(256), 0, stream, W2, Wt2);
  hipLaunchKernelGGL(wconv_k, dim3(64), dim3(256), 0, stream, W3, Wt3);
  hipLaunchKernelGGL(xconv_k, dim3(2048), dim3(256), 0, stream, x, xb, Nn * 32);

  hipLaunchKernelGGL(dense_mfma_k, dim3(dense_grid), dim3(256), 0, stream, xb, Wt1, Hb, Nn);
  hipLaunchKernelGGL(agg_k,        dim3(agg_grid),   dim3(256), 0, stream, Hb, edata, rowp, counts, dinv, b1, O1, Nn);
  hipLaunchKernelGGL(dense_mfma_k, dim3(dense_grid), dim3(256), 0, stream, O1, Wt2, Hb, Nn);
  hipLaunchKernelGGL(agg_k,        dim3(agg_grid),   dim3(256), 0, stream, Hb, edata, rowp, counts, dinv, b2, O2, Nn);
  hipLaunchKernelGGL(dense_mfma_k, dim3(dense_grid), dim3(256), 0, stream, O2, Wt3, Hb, Nn);
  hipLaunchKernelGGL(agg_k,        dim3(agg_grid),   dim3(256), 0, stream, Hb, edata, rowp, counts, dinv, b3, O3, Nn);
  hipLaunchKernelGGL(final_k, dim3((Nn + 255) / 256), dim3(256), 0, stream, O1, O2, O3, Wlin, blin, out, Nn);
}